// Round 8
// baseline (797.547 us; speedup 1.0000x reference)
//
#include <hip/hip_runtime.h>
#include <hip/hip_bf16.h>
#include <cstdint>
#include <cstddef>

#define BS 2
#define SLEN 4096
#define DIM 2048
#define INNER 1024
#define NEXP 16
#define CAP 512
#define TPE (BS*CAP)      // 1024 tokens per expert
#define NTOK (BS*SLEN)    // 8192

typedef __attribute__((ext_vector_type(4))) float f32x4;
typedef __attribute__((ext_vector_type(8))) short s16x8;

static __device__ __forceinline__ unsigned short f2bf(float f){
  unsigned u = __float_as_uint(f);
  u += 0x7FFFu + ((u >> 16) & 1u);   // RNE
  return (unsigned short)(u >> 16);
}
static __device__ __forceinline__ float sigmoidf_(float x){ return 1.0f/(1.0f+expf(-x)); }

static __device__ __forceinline__ void gload16(const unsigned short* g, short* l){
  __builtin_amdgcn_global_load_lds(
      (const __attribute__((address_space(1))) void*)g,
      (__attribute__((address_space(3))) void*)l, 16, 0, 0);
}

// ---------------- cast fp32 -> bf16 (vectorized) ----------------
__global__ __launch_bounds__(256) void cast_kernel(const float* __restrict__ in,
    unsigned short* __restrict__ out, long n){
  long i = ((long)blockIdx.x*256 + threadIdx.x)*8;
  if (i >= n) return;
  f32x4 a = *reinterpret_cast<const f32x4*>(in+i);
  f32x4 b = *reinterpret_cast<const f32x4*>(in+i+4);
  s16x8 o;
  o[0]=(short)f2bf(a[0]); o[1]=(short)f2bf(a[1]); o[2]=(short)f2bf(a[2]); o[3]=(short)f2bf(a[3]);
  o[4]=(short)f2bf(b[0]); o[5]=(short)f2bf(b[1]); o[6]=(short)f2bf(b[2]); o[7]=(short)f2bf(b[3]);
  *reinterpret_cast<s16x8*>(out+i) = o;
}

// ------------- transpose + cast v2: 64x64 tiles, vectorized both sides -------------
// in (R x C) fp32 -> out (C x R) bf16.  R, C multiples of 64.
__global__ __launch_bounds__(256) void transpose_cast_kernel(const float* __restrict__ in,
    unsigned short* __restrict__ out, int R, int C){
  __shared__ float t[64][65];
  const size_t mat = blockIdx.z;
  const float* src = in + mat*(size_t)R*C;
  unsigned short* dst = out + mat*(size_t)R*C;
  const int c0 = blockIdx.x*64, r0 = blockIdx.y*64;
  const int tid = threadIdx.x;
  const int tr = tid >> 4, tc4 = (tid & 15)*4;
  #pragma unroll
  for (int i=0;i<4;i++){
    f32x4 v = *reinterpret_cast<const f32x4*>(src + (size_t)(r0+tr+16*i)*C + c0 + tc4);
    t[tr+16*i][tc4+0]=v[0]; t[tr+16*i][tc4+1]=v[1]; t[tr+16*i][tc4+2]=v[2]; t[tr+16*i][tc4+3]=v[3];
  }
  __syncthreads();
  const int sc = tid >> 3, srs = (tid & 7)*8;
  #pragma unroll
  for (int i=0;i<2;i++){
    int cc = sc + 32*i;
    s16x8 o;
    #pragma unroll
    for (int j=0;j<8;j++) o[j] = (short)f2bf(t[srs+j][cc]);
    *reinterpret_cast<s16x8*>(dst + (size_t)(c0+cc)*R + r0 + srs) = o;
  }
}

// -------- fp32 transpose of gate_w hidden half: gwT[e][d] = gate_w[DIM+d][e] --------
__global__ __launch_bounds__(256) void gwT_kernel(const float* __restrict__ gate_w,
    float* __restrict__ gwT){
  int d = blockIdx.x*256 + threadIdx.x;
  #pragma unroll
  for (int e=0;e<NEXP;e++)
    gwT[(size_t)e*DIM + d] = gate_w[(size_t)(DIM+d)*NEXP + e];
}

// ---------------- timestep part of router logits: tpart[b][e] ----------------
__global__ __launch_bounds__(256) void tpart_kernel(const float* __restrict__ timestep,
    const float* __restrict__ gate_w, float* __restrict__ tpart){
  int b = blockIdx.x >> 4, e = blockIdx.x & 15;
  float acc = 0.f;
  for (int d = threadIdx.x; d < DIM; d += 256)
    acc += timestep[b*DIM + d] * gate_w[(size_t)d*NEXP + e];
  #pragma unroll
  for (int o=32;o>0;o>>=1) acc += __shfl_down(acc, o);
  __shared__ float red[4];
  int lane = threadIdx.x & 63, wid = threadIdx.x >> 6;
  if (lane==0) red[wid] = acc;
  __syncthreads();
  if (threadIdx.x==0) tpart[blockIdx.x] = red[0]+red[1]+red[2]+red[3];
}

// ------- router v2: lane = (token_sub, expert); full-K dot per lane, no reduce -------
__global__ __launch_bounds__(256) void router2_kernel(const float* __restrict__ xu,
    const float* __restrict__ gwT, const float* __restrict__ tpart,
    float* __restrict__ scores){
  const int lane = threadIdx.x & 63, wv = threadIdx.x >> 6;
  const int tsub = lane >> 4, e = lane & 15;
  const int tok = blockIdx.x*16 + wv*4 + tsub;
  const int b = tok >> 12, s = tok & (SLEN-1);
  const float* xr = xu + (size_t)tok*DIM;
  const float* gr = gwT + (size_t)e*DIM;
  float a0=0.f, a1=0.f, a2=0.f, a3=0.f;
  for (int k = 0; k < DIM; k += 16){
    f32x4 x0 = *reinterpret_cast<const f32x4*>(xr+k);
    f32x4 x1 = *reinterpret_cast<const f32x4*>(xr+k+4);
    f32x4 x2 = *reinterpret_cast<const f32x4*>(xr+k+8);
    f32x4 x3 = *reinterpret_cast<const f32x4*>(xr+k+12);
    f32x4 g0 = *reinterpret_cast<const f32x4*>(gr+k);
    f32x4 g1 = *reinterpret_cast<const f32x4*>(gr+k+4);
    f32x4 g2 = *reinterpret_cast<const f32x4*>(gr+k+8);
    f32x4 g3 = *reinterpret_cast<const f32x4*>(gr+k+12);
    a0 += x0[0]*g0[0] + x0[1]*g0[1] + x0[2]*g0[2] + x0[3]*g0[3];
    a1 += x1[0]*g1[0] + x1[1]*g1[1] + x1[2]*g1[2] + x1[3]*g1[3];
    a2 += x2[0]*g2[0] + x2[1]*g2[1] + x2[2]*g2[2] + x2[3]*g2[3];
    a3 += x3[0]*g3[0] + x3[1]*g3[1] + x3[2]*g3[2] + x3[3]*g3[3];
  }
  float v = (a0+a1)+(a2+a3) + tpart[b*NEXP+e];
  scores[((size_t)(b*NEXP+e))*SLEN + s] = sigmoidf_(v);
}

// ---------------- top-512 per (b,e) via bitonic sort in LDS ----------------
__global__ __launch_bounds__(1024) void topk_kernel(const float* __restrict__ scores,
    int* __restrict__ tok_idx, float* __restrict__ gate_raw, float* __restrict__ token_sums){
  __shared__ unsigned long long keys[SLEN];
  const int b = blockIdx.x >> 4, e = blockIdx.x & 15;
  const float* sc = scores + (size_t)blockIdx.x * SLEN;
  for (int i = threadIdx.x; i < SLEN; i += 1024){
    unsigned bits = __float_as_uint(sc[i]);
    keys[i] = ((unsigned long long)bits << 32) | (unsigned)(SLEN-1-i);
  }
  __syncthreads();
  for (int k = 2; k <= SLEN; k <<= 1){
    for (int j = k >> 1; j > 0; j >>= 1){
      for (int i = threadIdx.x; i < SLEN; i += 1024){
        int ixj = i ^ j;
        if (ixj > i){
          bool up = ((i & k) == 0);
          unsigned long long a = keys[i], c = keys[ixj];
          if ((a > c) == up){ keys[i] = c; keys[ixj] = a; }
        }
      }
      __syncthreads();
    }
  }
  for (int c = threadIdx.x; c < CAP; c += 1024){
    unsigned long long kk = keys[SLEN-1-c];
    int s = (SLEN-1) - (int)(kk & 0xFFFFFFFFull);
    float g = __uint_as_float((unsigned)(kk >> 32));
    int slot = (e*BS + b)*CAP + c;
    tok_idx[slot]  = s;
    gate_raw[slot] = g;
    atomicAdd(&token_sums[b*SLEN + s], g);
  }
}

// ============ occupancy-overlap GEMM: BM=128, virtBN=256, BK=32, 48KB LDS ============
// 8 waves (2M x 4N), per-wave C = 64x64 (acc[4][4] = 64 VGPR). 2 blocks/CU
// co-resident (launch_bounds(512,4)) provide the MFMA<->LDS overlap that the
// single-block 256^2 config structurally lacked. Swizzle for 64B rows:
// 16B-slot ^= (row>>1)&3 (2 lanes/bank on fragment reads = free); staging
// source pre-swizzled with the same involution: scol = 8*((l&3)^((l>>3)&3)).
// Counted vmcnt(3) keeps the next K-tile's 3 loads in flight across barriers.

template<bool GLU, bool GATHER, bool ROUTED, bool SILU_FIRST, int K>
__global__ __launch_bounds__(512, 4) void gemm8_kernel(
    const unsigned short* __restrict__ A,
    const unsigned short* __restrict__ B,
    size_t bstride,
    const int* __restrict__ tok_idx,
    const float* __restrict__ gate_raw,
    const float* __restrict__ token_sums,
    unsigned short* __restrict__ actOut,
    float* __restrict__ fOut)
{
  constexpr int NT = K/32;
  const int e = blockIdx.z;
  const int tid = threadIdx.x;
  const int lane = tid & 63, w = tid >> 6;        // 8 waves
  const int wr = w >> 2, wc = w & 3;              // 2M x 4N
  const int lr = lane & 15, lg = lane >> 4;
  const int m0 = blockIdx.y * 128;
  const int c0 = blockIdx.x * (GLU ? 128 : 256);

  __shared__ short Ab[2][4096];   // [buf][128 rows x 32 k] swizzled storage
  __shared__ short Bb[2][8192];   // [buf][256 virt rows x 32 k]

  // ---- staging: chunk=1KB=16 rows x 64B; lane l -> row l>>2, slot l&3;
  // source slot = (l&3) ^ ((l>>3)&3)  (involution with read swizzle)
  const int srow4 = lane >> 2;
  const int scol  = 8 * ((lane & 3) ^ ((lane >> 3) & 3));

  const unsigned short* pA;
  const unsigned short* pB0;
  const unsigned short* pB1;
  {
    int v = w*16 + srow4;                 // A row 0..127
    long garow;
    if (GLU && GATHER){
      int idx = m0 + v;
      int b = idx >> 9;
      int t = tok_idx[(e*BS + b)*CAP + (idx & (CAP-1))];
      garow = (long)b*SLEN + t;
    } else {
      garow = (ROUTED ? (long)e*TPE : 0L) + m0 + v;
    }
    pA = A + (size_t)garow*K + scol;
    #pragma unroll
    for (int j=0;j<2;j++){
      int vb = w*32 + j*16 + srow4;       // B virt row 0..255
      long brow;
      if (GLU) brow = (long)(((vb>>4)&1)*INNER + c0 + ((vb>>5)*16) + (vb & 15));
      else     brow = (long)(c0 + vb);
      const unsigned short* p = B + (size_t)e*bstride + (size_t)brow*K + scol;
      if (j==0) pB0 = p; else pB1 = p;
    }
  }

  auto stage = [&](int tb){
    gload16(pA,  &Ab[tb][w*512]);
    gload16(pB0, &Bb[tb][(2*w+0)*512]);
    gload16(pB1, &Bb[tb][(2*w+1)*512]);
    pA += 32; pB0 += 32; pB1 += 32;
  };

  // ---- fragment reads: row r, want k-slot lg -> LDS slot lg ^ ((r>>1)&3).
  // For all our rows, (r>>1)&3 == (lr>>1)&3 (mi/ni/wr/wc contribute multiples of 8).
  const int slot0 = 8 * (lg ^ ((lr >> 1) & 3));
  const int aBase = (64*wr + lr)*32 + slot0;
  const int bBase = (64*wc + lr)*32 + slot0;

  s16x8 af[4], bf[4];
  f32x4 acc[4][4];
  #pragma unroll
  for (int i=0;i<4;i++)
    #pragma unroll
    for (int j=0;j<4;j++) acc[i][j] = (f32x4)0.0f;

  auto ldAB = [&](int tb){
    #pragma unroll
    for (int i=0;i<4;i++) af[i] = *reinterpret_cast<const s16x8*>(&Ab[tb][aBase + i*512]);
    #pragma unroll
    for (int n=0;n<4;n++) bf[n] = *reinterpret_cast<const s16x8*>(&Bb[tb][bBase + n*512]);
  };
  auto mma16 = [&](){
    #pragma unroll
    for (int i=0;i<4;i++)
      #pragma unroll
      for (int n=0;n<4;n++)
        acc[i][n] = __builtin_amdgcn_mfma_f32_16x16x32_bf16(af[i], bf[n], acc[i][n], 0, 0, 0);
  };

  // prologue: t=0 -> buf0, t=1 -> buf1; wait t0 (3 loads of t1 in flight)
  stage(0); stage(1);
  asm volatile("s_waitcnt vmcnt(3)" ::: "memory");
  __builtin_amdgcn_sched_barrier(0);
  __builtin_amdgcn_s_barrier();

  #pragma unroll 1
  for (int t = 0; t < NT; ++t){
    ldAB(t & 1);
    asm volatile("s_waitcnt lgkmcnt(0)" ::: "memory");   // my reads done
    __builtin_amdgcn_sched_barrier(0);
    __builtin_amdgcn_s_barrier();                        // all waves' reads done
    if (t + 2 < NT) stage(t & 1);                        // overwrite safe now
    mma16();
    __builtin_amdgcn_sched_barrier(0);
    if (t + 2 < NT) { asm volatile("s_waitcnt vmcnt(3)" ::: "memory"); }
    else            { asm volatile("s_waitcnt vmcnt(0)" ::: "memory"); }
    __builtin_amdgcn_sched_barrier(0);
    __builtin_amdgcn_s_barrier();                        // next buf ready
  }

  if (GLU){
    const size_t rowbase = GATHER ? (size_t)e*TPE : (size_t)0;
    #pragma unroll
    for (int mi=0; mi<4; mi++){
      int row = m0 + 64*wr + 16*mi + 4*lg;
      #pragma unroll
      for (int p=0;p<2;p++){
        int col = c0 + 32*wc + 16*p + lr;
        #pragma unroll
        for (int r=0;r<4;r++){
          float g = acc[mi][2*p][r], u = acc[mi][2*p+1][r];
          float a = SILU_FIRST ? (g*sigmoidf_(g))*u : g*(u*sigmoidf_(u));
          actOut[(rowbase + row + r)*(size_t)INNER + col] = f2bf(a);
        }
      }
    }
  } else if (ROUTED){
    #pragma unroll
    for (int mi=0; mi<4; mi++){
      #pragma unroll
      for (int r=0;r<4;r++){
        int slot = m0 + 64*wr + 16*mi + 4*lg + r;        // 0..1023 within expert
        int b = slot >> 9;
        int gs = (e*BS + b)*CAP + (slot & (CAP-1));
        int t = tok_idx[gs];
        size_t orow = (size_t)b*SLEN + t;
        float gn = gate_raw[gs] / (token_sums[orow] + 1e-12f);
        #pragma unroll
        for (int ni=0;ni<4;ni++){
          int col = c0 + 64*wc + 16*ni + lr;
          atomicAdd(&fOut[orow*DIM + col], acc[mi][ni][r]*gn);
        }
      }
    }
  } else {
    #pragma unroll
    for (int mi=0; mi<4; mi++){
      #pragma unroll
      for (int r=0;r<4;r++){
        size_t row = (size_t)(m0 + 64*wr + 16*mi + 4*lg + r);
        #pragma unroll
        for (int ni=0;ni<4;ni++){
          int col = c0 + 64*wc + 16*ni + lr;
          fOut[row*DIM + col] = acc[mi][ni][r];
        }
      }
    }
  }
}

extern "C" void kernel_launch(void* const* d_in, const int* in_sizes, int n_in,
                              void* d_out, int out_size, void* d_ws, size_t ws_size,
                              hipStream_t stream) {
  (void)in_sizes; (void)n_in; (void)out_size; (void)ws_size;
  const float* hidden   = (const float*)d_in[0];
  const float* xu       = (const float*)d_in[1];
  const float* timestep = (const float*)d_in[2];
  const float* gate_w   = (const float*)d_in[3];
  const float* gup      = (const float*)d_in[4];
  const float* dwn      = (const float*)d_in[5];
  const float* shin     = (const float*)d_in[6];
  const float* shout    = (const float*)d_in[7];
  float* out = (float*)d_out;

  char* base = (char*)d_ws;
  size_t off = 0;
  auto alloc = [&](size_t bytes)->char*{
    char* p = base + off; off = (off + bytes + 255) & ~(size_t)255; return p;
  };
  float* token_sums = (float*)alloc((size_t)NTOK*4);
  float* tpart      = (float*)alloc((size_t)BS*NEXP*4);
  float* gwT        = (float*)alloc((size_t)NEXP*DIM*4);
  float* scores     = (float*)alloc((size_t)BS*NEXP*SLEN*4);
  int*   tok_idx    = (int*)  alloc((size_t)NEXP*BS*CAP*4);
  float* gate_raw   = (float*)alloc((size_t)NEXP*BS*CAP*4);
  unsigned short* hid_bf = (unsigned short*)alloc((size_t)NTOK*DIM*2);
  unsigned short* gupT   = (unsigned short*)alloc((size_t)NEXP*2*INNER*DIM*2);
  unsigned short* dwnT   = (unsigned short*)alloc((size_t)NEXP*DIM*INNER*2);
  unsigned short* shinT  = (unsigned short*)alloc((size_t)2*INNER*DIM*2);
  unsigned short* shoutT = (unsigned short*)alloc((size_t)DIM*INNER*2);
  unsigned short* act_s  = (unsigned short*)alloc((size_t)NTOK*INNER*2);
  unsigned short* act_r  = (unsigned short*)alloc((size_t)NEXP*TPE*INNER*2);
  (void)alloc(1<<16);   // pad

  hipMemsetAsync(token_sums, 0, (size_t)NTOK*4, stream);
  cast_kernel<<<(NTOK*DIM)/2048, 256, 0, stream>>>(hidden, hid_bf, (long)NTOK*DIM);
  transpose_cast_kernel<<<dim3((2*INNER)/64, DIM/64, NEXP), 256, 0, stream>>>(gup, gupT, DIM, 2*INNER);
  transpose_cast_kernel<<<dim3(DIM/64, INNER/64, NEXP), 256, 0, stream>>>(dwn, dwnT, INNER, DIM);
  transpose_cast_kernel<<<dim3((2*INNER)/64, DIM/64, 1), 256, 0, stream>>>(shin, shinT, DIM, 2*INNER);
  transpose_cast_kernel<<<dim3(DIM/64, INNER/64, 1), 256, 0, stream>>>(shout, shoutT, INNER, DIM);

  gwT_kernel<<<DIM/256, 256, 0, stream>>>(gate_w, gwT);
  tpart_kernel<<<BS*NEXP, 256, 0, stream>>>(timestep, gate_w, tpart);
  router2_kernel<<<NTOK/16, 256, 0, stream>>>(xu, gwT, tpart, scores);
  topk_kernel<<<BS*NEXP, 1024, 0, stream>>>(scores, tok_idx, gate_raw, token_sums);

  // gemm1 shared: act_s = h0 * silu(h1)   (GLU, no gather, silu on SECOND half)
  gemm8_kernel<true,false,false,false,DIM><<<dim3(INNER/128, NTOK/128, 1), 512, 0, stream>>>(
      hid_bf, shinT, 0, nullptr, nullptr, nullptr, act_s, nullptr);
  // gemm1 routed: act_r = silu(g) * u     (GLU, gather, silu on FIRST half)
  gemm8_kernel<true,true,false,true,DIM><<<dim3(INNER/128, TPE/128, NEXP), 512, 0, stream>>>(
      hid_bf, gupT, (size_t)(2*INNER)*DIM, tok_idx, nullptr, nullptr, act_r, nullptr);
  // gemm2 shared: out = act_s @ shoutT (plain store initializes d_out)
  gemm8_kernel<false,false,false,false,INNER><<<dim3(DIM/256, NTOK/128, 1), 512, 0, stream>>>(
      act_s, shoutT, 0, nullptr, nullptr, nullptr, nullptr, out);
  // gemm2 routed: atomicAdd(out, acc * gate/(sums+eps))
  gemm8_kernel<false,false,true,false,INNER><<<dim3(DIM/256, TPE/128, NEXP), 512, 0, stream>>>(
      act_r, dwnT, (size_t)DIM*INNER, tok_idx, gate_raw, token_sums, nullptr, out);
}